// Round 1
// baseline (238.294 us; speedup 1.0000x reference)
//
#include <hip/hip_runtime.h>

// HexPool: out[r, :] = max_{k<7} x[idx[r,k], :], D=64 fp32, idx < N_OUT.
// Memory-bound gather; 16 lanes/row, float4 per lane (256B coalesced per row).

constexpr int N_OUT = 163842;
constexpr int D = 64;
constexpr int K = 7;
constexpr int LANES_PER_ROW = D / 4;  // 16

__global__ __launch_bounds__(256) void HexPool_kernel(
    const float* __restrict__ x,
    const int* __restrict__ idx,
    float* __restrict__ out)
{
    int tid = blockIdx.x * blockDim.x + threadIdx.x;
    int row = tid / LANES_PER_ROW;
    int cg  = (tid & (LANES_PER_ROW - 1)) << 2;  // column start (multiple of 4)
    if (row >= N_OUT) return;

    const int* ip = idx + (size_t)row * K;

    // First gathered row initializes the max (input has no NaNs; -inf init
    // would also be fine, this saves 4 fmax).
    int j0 = ip[0];
    float4 m = *reinterpret_cast<const float4*>(x + (size_t)j0 * D + cg);

#pragma unroll
    for (int k = 1; k < K; ++k) {
        int j = ip[k];
        const float4 v = *reinterpret_cast<const float4*>(x + (size_t)j * D + cg);
        m.x = fmaxf(m.x, v.x);
        m.y = fmaxf(m.y, v.y);
        m.z = fmaxf(m.z, v.z);
        m.w = fmaxf(m.w, v.w);
    }
    *reinterpret_cast<float4*>(out + (size_t)row * D + cg) = m;
}

extern "C" void kernel_launch(void* const* d_in, const int* in_sizes, int n_in,
                              void* d_out, int out_size, void* d_ws, size_t ws_size,
                              hipStream_t stream) {
    const float* x   = (const float*)d_in[0];
    const int*   idx = (const int*)d_in[1];
    float*       out = (float*)d_out;

    const long total_threads = (long)N_OUT * LANES_PER_ROW;  // 2,621,472
    const int  block = 256;
    const int  grid  = (int)((total_threads + block - 1) / block);  // 10241

    HexPool_kernel<<<grid, block, 0, stream>>>(x, idx, out);
}

// Round 2
// 237.526 us; speedup vs baseline: 1.0032x; 1.0032x over previous
//
#include <hip/hip_runtime.h>

// HexPool: out[r, :] = max_{k<7} x[idx[r,k], :], D=64 fp32, idx < N_OUT.
// Memory-bound random gather. 16 lanes/row, float4/lane (256B per gathered row).
// R2: 2 rows per thread (14 outstanding gathers for latency hiding),
//     nontemporal stores (out is streamed; keep L2 for the hot x working set).

constexpr int N_OUT = 163842;
constexpr int D = 64;
constexpr int K = 7;
constexpr int ROWS_PER_THREAD = 2;
constexpr int GROUPS = N_OUT / ROWS_PER_THREAD;  // 81921, exact

typedef float v4f __attribute__((ext_vector_type(4)));

__global__ __launch_bounds__(256) void HexPool_kernel(
    const float* __restrict__ x,
    const int* __restrict__ idx,
    float* __restrict__ out)
{
    int tid = blockIdx.x * blockDim.x + threadIdx.x;
    int g   = tid >> 4;              // 16-lane group id -> row pair
    int cg  = (tid & 15) << 2;       // column start (multiple of 4)
    if (g >= GROUPS) return;

    const int r0 = g * ROWS_PER_THREAD;
    const int* ip = idx + (size_t)r0 * K;

    // Load all 14 indices up front (two contiguous 28B runs).
    int j[ROWS_PER_THREAD][K];
#pragma unroll
    for (int r = 0; r < ROWS_PER_THREAD; ++r)
#pragma unroll
        for (int k = 0; k < K; ++k)
            j[r][k] = ip[r * K + k];

    // Issue all 14 gathers before reducing — max ILP for the memory system.
    v4f v[ROWS_PER_THREAD][K];
#pragma unroll
    for (int r = 0; r < ROWS_PER_THREAD; ++r)
#pragma unroll
        for (int k = 0; k < K; ++k)
            v[r][k] = *reinterpret_cast<const v4f*>(x + (size_t)j[r][k] * D + cg);

#pragma unroll
    for (int r = 0; r < ROWS_PER_THREAD; ++r) {
        v4f m = v[r][0];
#pragma unroll
        for (int k = 1; k < K; ++k) {
            m.x = fmaxf(m.x, v[r][k].x);
            m.y = fmaxf(m.y, v[r][k].y);
            m.z = fmaxf(m.z, v[r][k].z);
            m.w = fmaxf(m.w, v[r][k].w);
        }
        // Streamed output, never re-read: nontemporal to spare L2 for x.
        __builtin_nontemporal_store(
            m, reinterpret_cast<v4f*>(out + (size_t)(r0 + r) * D + cg));
    }
}

extern "C" void kernel_launch(void* const* d_in, const int* in_sizes, int n_in,
                              void* d_out, int out_size, void* d_ws, size_t ws_size,
                              hipStream_t stream) {
    const float* x   = (const float*)d_in[0];
    const int*   idx = (const int*)d_in[1];
    float*       out = (float*)d_out;

    const long total_threads = (long)GROUPS * 16;  // 1,310,736
    const int  block = 256;
    const int  grid  = (int)((total_threads + block - 1) / block);  // 5121

    HexPool_kernel<<<grid, block, 0, stream>>>(x, idx, out);
}